// Round 1
// baseline (1319.155 us; speedup 1.0000x reference)
//
#include <hip/hip_runtime.h>
#include <math.h>

// Problem constants (from reference)
constexpr int KIN = 128;   // IN_F

// ---------------- graph setup kernels ----------------

__global__ void count_dst(const int* __restrict__ dst, int* __restrict__ cnt, int E) {
    int e = blockIdx.x * blockDim.x + threadIdx.x;
    if (e < E) atomicAdd(&cnt[dst[e]], 1);
}

__global__ void make_dinv(const int* __restrict__ cnt, float* __restrict__ dinv, int n) {
    int v = blockIdx.x * blockDim.x + threadIdx.x;
    if (v < n) dinv[v] = 1.0f / sqrtf((float)(cnt[v] + 1));  // +1 self loop
}

// pass 1: per-block sums of cnt
__global__ void scan_reduce(const int* __restrict__ cnt, int* __restrict__ bsum, int n) {
    __shared__ int s[256];
    int t = threadIdx.x;
    int i = blockIdx.x * 256 + t;
    s[t] = (i < n) ? cnt[i] : 0;
    __syncthreads();
    for (int off = 128; off > 0; off >>= 1) {
        if (t < off) s[t] += s[t + off];
        __syncthreads();
    }
    if (t == 0) bsum[blockIdx.x] = s[0];
}

// pass 2: single-block exclusive scan of block sums (nb <= 512)
__global__ void scan_blocksums(const int* __restrict__ bsum, int* __restrict__ bpre, int nb) {
    __shared__ int s[512];
    int t = threadIdx.x;
    int val = (t < nb) ? bsum[t] : 0;
    s[t] = val;
    __syncthreads();
    for (int off = 1; off < 512; off <<= 1) {
        int x = (t >= off) ? s[t - off] : 0;
        __syncthreads();
        s[t] += x;
        __syncthreads();
    }
    if (t < nb) bpre[t] = s[t] - val;  // exclusive
}

// pass 3: per-block exclusive scan + block offset -> row_ptr
__global__ void scan_scatter(const int* __restrict__ cnt, const int* __restrict__ bpre,
                             int* __restrict__ row_ptr, int n, int total) {
    __shared__ int s[256];
    int t = threadIdx.x;
    int i = blockIdx.x * 256 + t;
    int val = (i < n) ? cnt[i] : 0;
    s[t] = val;
    __syncthreads();
    for (int off = 1; off < 256; off <<= 1) {
        int x = (t >= off) ? s[t - off] : 0;
        __syncthreads();
        s[t] += x;
        __syncthreads();
    }
    if (i < n) row_ptr[i] = bpre[blockIdx.x] + s[t] - val;
    if (i == n - 1) row_ptr[n] = total;
}

__global__ void fill_csr(const int* __restrict__ src, const int* __restrict__ dst,
                         const int* __restrict__ row_ptr, int* __restrict__ fill,
                         int* __restrict__ csr_src, int E) {
    int e = blockIdx.x * blockDim.x + threadIdx.x;
    if (e < E) {
        int d = dst[e];
        int pos = row_ptr[d] + atomicAdd(&fill[d], 1);
        csr_src[pos] = src[e];
    }
}

// ---------------- dense kernels ----------------

// out[v,f] = (SCALE ? dinv[v] : 1) * sum_k in[v,k]*W[k,f]
template <int K, int F, bool SCALE>
__global__ void gemm_rows(const float* __restrict__ in, const float* __restrict__ W,
                          const float* __restrict__ dinv, float* __restrict__ out, int n) {
    __shared__ float Ws[K * F];
    int t = threadIdx.x;
    for (int i = t; i < K * F; i += 256) Ws[i] = W[i];
    __syncthreads();
    constexpr int ROWS = 256 / F;
    int v = blockIdx.x * ROWS + t / F;
    int f = t % F;
    if (v >= n) return;
    const float4* in4 = (const float4*)(in + (size_t)v * K);
    float acc = 0.f;
#pragma unroll
    for (int k4 = 0; k4 < K / 4; ++k4) {
        float4 a = in4[k4];
        acc = fmaf(a.x, Ws[(4 * k4 + 0) * F + f], acc);
        acc = fmaf(a.y, Ws[(4 * k4 + 1) * F + f], acc);
        acc = fmaf(a.z, Ws[(4 * k4 + 2) * F + f], acc);
        acc = fmaf(a.w, Ws[(4 * k4 + 3) * F + f], acc);
    }
    if (SCALE) acc *= dinv[v];
    out[(size_t)v * F + f] = acc;
}

// GCN aggregation: out[v,f] = relu(dinv[v]*(Hs[v,f] + sum_in Hs[u,f]) + b[f]) (+res)
template <int F, bool RES>
__global__ void gcn_agg(const float* __restrict__ Hs, const int* __restrict__ row_ptr,
                        const int* __restrict__ csr_src, const float* __restrict__ dinv,
                        const float* __restrict__ bias, const float* __restrict__ res,
                        float* __restrict__ out, int n) {
    int idx = blockIdx.x * blockDim.x + threadIdx.x;
    int v = idx / F;
    int f = idx % F;
    if (v >= n) return;
    float acc = Hs[(size_t)v * F + f];  // self loop (pre-scaled by dinv[v])
    int beg = row_ptr[v], end = row_ptr[v + 1];
    for (int e = beg; e < end; ++e) {
        int u = csr_src[e];
        acc += Hs[(size_t)u * F + f];
    }
    float o = fmaxf(dinv[v] * acc + bias[f], 0.f);
    if (RES) o += res[(size_t)v * F + f];  // h = res + relu(gcn(h))
    out[(size_t)v * F + f] = o;
}

// per (node, head): a_s, a_d
__global__ void gat_att(const float* __restrict__ H, const float* __restrict__ att_src,
                        const float* __restrict__ att_dst, float* __restrict__ a_s,
                        float* __restrict__ a_d, int n) {
    int idx = blockIdx.x * blockDim.x + threadIdx.x;
    if (idx >= n * 4) return;
    int v = idx >> 2, hd = idx & 3;
    const float4* h4 = (const float4*)(H + (size_t)v * 64 + hd * 16);
    const float4* s4 = (const float4*)(att_src + hd * 16);
    const float4* d4 = (const float4*)(att_dst + hd * 16);
    float as = 0.f, ad = 0.f;
#pragma unroll
    for (int c = 0; c < 4; ++c) {
        float4 h = h4[c], s = s4[c], d = d4[c];
        as += h.x * s.x + h.y * s.y + h.z * s.z + h.w * s.w;
        ad += h.x * d.x + h.y * d.y + h.z * d.z + h.w * d.w;
    }
    a_s[idx] = as;
    a_d[idx] = ad;
}

// GAT aggregation with online segment softmax. One wave (64 lanes) per node:
// lane = head*16 + channel. Self edge seeds the softmax state.
__global__ void gat_agg(const float* __restrict__ H, const int* __restrict__ row_ptr,
                        const int* __restrict__ csr_src, const float* __restrict__ a_s,
                        const float* __restrict__ a_d, const float* __restrict__ bias,
                        float* __restrict__ out, int n) {
    int idx = blockIdx.x * blockDim.x + threadIdx.x;
    int v = idx >> 6;
    int lane = idx & 63;
    if (v >= n) return;
    int hd = lane >> 4;
    float adv = a_d[v * 4 + hd];
    float e0 = a_s[v * 4 + hd] + adv;
    e0 = (e0 >= 0.f) ? e0 : 0.2f * e0;
    float m = e0;
    float l = 1.0f;                          // exp(e0 - m) = 1
    float acc = H[(size_t)v * 64 + lane];    // p_self * H[v]
    int beg = row_ptr[v], end = row_ptr[v + 1];
    for (int e = beg; e < end; ++e) {
        int u = csr_src[e];
        float ev = a_s[u * 4 + hd] + adv;
        ev = (ev >= 0.f) ? ev : 0.2f * ev;
        float nm = fmaxf(m, ev);
        float sc = __expf(m - nm);
        float p = __expf(ev - nm);
        l = l * sc + p;
        acc = acc * sc + p * H[(size_t)u * 64 + lane];
        m = nm;
    }
    out[(size_t)v * 64 + lane] = fmaxf(acc / (l + 1e-16f) + bias[lane], 0.f);
}

// final: out[v] = relu(sum_f h[v,f]*Wl[f] + bl), one wave per node
__global__ void final_linear(const float* __restrict__ H, const float* __restrict__ Wl,
                             const float* __restrict__ bl, float* __restrict__ out, int n) {
    int idx = blockIdx.x * blockDim.x + threadIdx.x;
    int v = idx >> 6, lane = idx & 63;
    if (v >= n) return;
    float p = H[(size_t)v * 64 + lane] * Wl[lane];
#pragma unroll
    for (int off = 32; off > 0; off >>= 1) p += __shfl_down(p, off);
    if (lane == 0) out[v] = fmaxf(p + bl[0], 0.f);
}

// ---------------- launch ----------------

extern "C" void kernel_launch(void* const* d_in, const int* in_sizes, int n_in,
                              void* d_out, int out_size, void* d_ws, size_t ws_size,
                              hipStream_t stream) {
    const float* x     = (const float*)d_in[0];
    const int*   ei    = (const int*)d_in[1];
    const float* W1    = (const float*)d_in[2];
    const float* b1    = (const float*)d_in[3];
    const float* W2    = (const float*)d_in[4];
    const float* b2    = (const float*)d_in[5];
    const float* W3    = (const float*)d_in[6];
    const float* b3    = (const float*)d_in[7];
    const float* Wg    = (const float*)d_in[8];
    const float* att_s = (const float*)d_in[9];
    const float* att_d = (const float*)d_in[10];
    const float* bg    = (const float*)d_in[11];
    const float* Wl    = (const float*)d_in[12];
    const float* bl    = (const float*)d_in[13];
    float* out = (float*)d_out;

    int n = in_sizes[0] / KIN;  // 100000
    int E = in_sizes[1] / 2;    // 1600000
    const int* srcp = ei;
    const int* dstp = ei + E;

    // workspace carve (256B aligned)
    char* w = (char*)d_ws;
    auto alloc = [&](size_t bytes) -> void* {
        void* p = (void*)w;
        w += (bytes + 255) & ~(size_t)255;
        return p;
    };
    int*   cnt     = (int*)alloc((size_t)n * 4);
    int*   row_ptr = (int*)alloc((size_t)(n + 1) * 4);
    int*   fillc   = (int*)alloc((size_t)n * 4);
    int*   bsum    = (int*)alloc(512 * 4);
    int*   bpre    = (int*)alloc(512 * 4);
    int*   csr     = (int*)alloc((size_t)E * 4);
    float* dinv    = (float*)alloc((size_t)n * 4);
    float* a_s     = (float*)alloc((size_t)n * 4 * 4);
    float* a_d     = (float*)alloc((size_t)n * 4 * 4);
    float* bufA    = (float*)alloc((size_t)n * 64 * 4);
    float* bufB    = (float*)alloc((size_t)n * 64 * 4);
    float* bufC    = (float*)alloc((size_t)n * 64 * 4);

    hipMemsetAsync(cnt, 0, (size_t)n * 4, stream);
    hipMemsetAsync(fillc, 0, (size_t)n * 4, stream);

    int nb = (n + 255) / 256;  // 391
    count_dst<<<(E + 255) / 256, 256, 0, stream>>>(dstp, cnt, E);
    make_dinv<<<nb, 256, 0, stream>>>(cnt, dinv, n);
    scan_reduce<<<nb, 256, 0, stream>>>(cnt, bsum, n);
    scan_blocksums<<<1, 512, 0, stream>>>(bsum, bpre, nb);
    scan_scatter<<<nb, 256, 0, stream>>>(cnt, bpre, row_ptr, n, E);
    fill_csr<<<(E + 255) / 256, 256, 0, stream>>>(srcp, dstp, row_ptr, fillc, csr, E);

    // Layer 1: GCN 128->32  (x -> bufB)
    gemm_rows<128, 32, true><<<(n + 7) / 8, 256, 0, stream>>>(x, W1, dinv, bufA, n);
    gcn_agg<32, false><<<(n * 32 + 255) / 256, 256, 0, stream>>>(bufA, row_ptr, csr, dinv, b1, nullptr, bufB, n);
    // Layer 2: GCN 32->64  (bufB -> bufB)
    gemm_rows<32, 64, true><<<(n + 3) / 4, 256, 0, stream>>>(bufB, W2, dinv, bufA, n);
    gcn_agg<64, false><<<(n * 64 + 255) / 256, 256, 0, stream>>>(bufA, row_ptr, csr, dinv, b2, nullptr, bufB, n);
    // GAT 1: bufB -> bufC
    gemm_rows<64, 64, false><<<(n + 3) / 4, 256, 0, stream>>>(bufB, Wg, nullptr, bufA, n);
    gat_att<<<(n * 4 + 255) / 256, 256, 0, stream>>>(bufA, att_s, att_d, a_s, a_d, n);
    gat_agg<<<(n * 64 + 255) / 256, 256, 0, stream>>>(bufA, row_ptr, csr, a_s, a_d, bg, bufC, n);
    // GCN 3 + residual: bufC -> bufB  (bufB = bufC + relu(gcn(bufC)))
    gemm_rows<64, 64, true><<<(n + 3) / 4, 256, 0, stream>>>(bufC, W3, dinv, bufA, n);
    gcn_agg<64, true><<<(n * 64 + 255) / 256, 256, 0, stream>>>(bufA, row_ptr, csr, dinv, b3, bufC, bufB, n);
    // GAT 2: bufB -> bufC
    gemm_rows<64, 64, false><<<(n + 3) / 4, 256, 0, stream>>>(bufB, Wg, nullptr, bufA, n);
    gat_att<<<(n * 4 + 255) / 256, 256, 0, stream>>>(bufA, att_s, att_d, a_s, a_d, n);
    gat_agg<<<(n * 64 + 255) / 256, 256, 0, stream>>>(bufA, row_ptr, csr, a_s, a_d, bg, bufC, n);
    // Final linear
    final_linear<<<(n * 64 + 255) / 256, 256, 0, stream>>>(bufC, Wl, bl, out, n);
}

// Round 2
// 960.003 us; speedup vs baseline: 1.3741x; 1.3741x over previous
//
#include <hip/hip_runtime.h>
#include <math.h>

constexpr int KIN = 128;   // IN_F

// ---------------- graph setup kernels ----------------

__global__ void count_dst(const int* __restrict__ dst, int* __restrict__ cnt, int E) {
    int e = blockIdx.x * blockDim.x + threadIdx.x;
    if (e < E) atomicAdd(&cnt[dst[e]], 1);
}

__global__ void make_dinv(const int* __restrict__ cnt, float* __restrict__ dinv, int n) {
    int v = blockIdx.x * blockDim.x + threadIdx.x;
    if (v < n) dinv[v] = 1.0f / sqrtf((float)(cnt[v] + 1));  // +1 self loop
}

__global__ void scan_reduce(const int* __restrict__ cnt, int* __restrict__ bsum, int n) {
    __shared__ int s[256];
    int t = threadIdx.x;
    int i = blockIdx.x * 256 + t;
    s[t] = (i < n) ? cnt[i] : 0;
    __syncthreads();
    for (int off = 128; off > 0; off >>= 1) {
        if (t < off) s[t] += s[t + off];
        __syncthreads();
    }
    if (t == 0) bsum[blockIdx.x] = s[0];
}

__global__ void scan_blocksums(const int* __restrict__ bsum, int* __restrict__ bpre, int nb) {
    __shared__ int s[512];
    int t = threadIdx.x;
    int val = (t < nb) ? bsum[t] : 0;
    s[t] = val;
    __syncthreads();
    for (int off = 1; off < 512; off <<= 1) {
        int x = (t >= off) ? s[t - off] : 0;
        __syncthreads();
        s[t] += x;
        __syncthreads();
    }
    if (t < nb) bpre[t] = s[t] - val;  // exclusive
}

__global__ void scan_scatter(const int* __restrict__ cnt, const int* __restrict__ bpre,
                             int* __restrict__ row_ptr, int n, int total) {
    __shared__ int s[256];
    int t = threadIdx.x;
    int i = blockIdx.x * 256 + t;
    int val = (i < n) ? cnt[i] : 0;
    s[t] = val;
    __syncthreads();
    for (int off = 1; off < 256; off <<= 1) {
        int x = (t >= off) ? s[t - off] : 0;
        __syncthreads();
        s[t] += x;
        __syncthreads();
    }
    if (i < n) row_ptr[i] = bpre[blockIdx.x] + s[t] - val;
    if (i == n - 1) row_ptr[n] = total;
}

__global__ void fill_csr(const int* __restrict__ src, const int* __restrict__ dst,
                         const int* __restrict__ row_ptr, int* __restrict__ fill,
                         int* __restrict__ csr_src, int E) {
    int e = blockIdx.x * blockDim.x + threadIdx.x;
    if (e < E) {
        int d = dst[e];
        int pos = row_ptr[d] + atomicAdd(&fill[d], 1);
        csr_src[pos] = src[e];
    }
}

// ---------------- dense kernels ----------------

template <int K, int F, bool SCALE>
__global__ void gemm_rows(const float* __restrict__ in, const float* __restrict__ W,
                          const float* __restrict__ dinv, float* __restrict__ out, int n) {
    __shared__ float Ws[K * F];
    int t = threadIdx.x;
    for (int i = t; i < K * F; i += 256) Ws[i] = W[i];
    __syncthreads();
    constexpr int ROWS = 256 / F;
    int v = blockIdx.x * ROWS + t / F;
    int f = t % F;
    if (v >= n) return;
    const float4* in4 = (const float4*)(in + (size_t)v * K);
    float acc = 0.f;
#pragma unroll
    for (int k4 = 0; k4 < K / 4; ++k4) {
        float4 a = in4[k4];
        acc = fmaf(a.x, Ws[(4 * k4 + 0) * F + f], acc);
        acc = fmaf(a.y, Ws[(4 * k4 + 1) * F + f], acc);
        acc = fmaf(a.z, Ws[(4 * k4 + 2) * F + f], acc);
        acc = fmaf(a.w, Ws[(4 * k4 + 3) * F + f], acc);
    }
    if (SCALE) acc *= dinv[v];
    out[(size_t)v * F + f] = acc;
}

// Wave-per-node GCN aggregation with multi-edge-slot float4 gathers.
// lane = slot*CG + cg; CG = F/4 channel groups, SLOTS = 64/CG edge slots.
template <int F, bool RES>
__global__ void gcn_agg_w(const float* __restrict__ Hs, const int* __restrict__ row_ptr,
                          const int* __restrict__ csr, const float* __restrict__ dinv,
                          const float* __restrict__ bias, const float* __restrict__ res,
                          float* __restrict__ out, int n) {
    constexpr int CG = F / 4;
    constexpr int SLOTS = 64 / CG;
    int idx = blockIdx.x * blockDim.x + threadIdx.x;
    int v = idx >> 6;
    int lane = idx & 63;
    if (v >= n) return;
    int cg = lane % CG;
    int slot = lane / CG;
    const float4* H4 = (const float4*)Hs;

    float4 acc = {0.f, 0.f, 0.f, 0.f};
    if (slot == 0) acc = H4[(size_t)v * CG + cg];  // self loop (pre-scaled by dinv[v])

    int beg = row_ptr[v], end = row_ptr[v + 1];
    int deg = end - beg;
    int iters = (deg + SLOTS - 1) / SLOTS;
    int e = beg + slot;
    int u = (e < end) ? csr[e] : v;
    bool val = e < end;
    for (int i = 0; i < iters; ++i) {
        int en = e + SLOTS;
        int un = (en < end) ? csr[en] : v;          // prefetch next index
        float4 h = H4[(size_t)u * CG + cg];
        float m = val ? 1.f : 0.f;
        acc.x = fmaf(m, h.x, acc.x);
        acc.y = fmaf(m, h.y, acc.y);
        acc.z = fmaf(m, h.z, acc.z);
        acc.w = fmaf(m, h.w, acc.w);
        e = en; u = un; val = en < end;
    }
    // butterfly reduce across slots
    for (int off = CG; off < 64; off <<= 1) {
        acc.x += __shfl_xor(acc.x, off);
        acc.y += __shfl_xor(acc.y, off);
        acc.z += __shfl_xor(acc.z, off);
        acc.w += __shfl_xor(acc.w, off);
    }
    if (slot == 0) {
        float dv = dinv[v];
        float4 o;
        o.x = fmaxf(fmaf(dv, acc.x, bias[4 * cg + 0]), 0.f);
        o.y = fmaxf(fmaf(dv, acc.y, bias[4 * cg + 1]), 0.f);
        o.z = fmaxf(fmaf(dv, acc.z, bias[4 * cg + 2]), 0.f);
        o.w = fmaxf(fmaf(dv, acc.w, bias[4 * cg + 3]), 0.f);
        if (RES) {
            const float4 r = ((const float4*)res)[(size_t)v * CG + cg];
            o.x += r.x; o.y += r.y; o.z += r.z; o.w += r.w;
        }
        ((float4*)out)[(size_t)v * CG + cg] = o;
    }
}

// per (node, head): a_s, a_d
__global__ void gat_att(const float* __restrict__ H, const float* __restrict__ att_src,
                        const float* __restrict__ att_dst, float* __restrict__ a_s,
                        float* __restrict__ a_d, int n) {
    int idx = blockIdx.x * blockDim.x + threadIdx.x;
    if (idx >= n * 4) return;
    int v = idx >> 2, hd = idx & 3;
    const float4* h4 = (const float4*)(H + (size_t)v * 64 + hd * 16);
    const float4* s4 = (const float4*)(att_src + hd * 16);
    const float4* d4 = (const float4*)(att_dst + hd * 16);
    float as = 0.f, ad = 0.f;
#pragma unroll
    for (int c = 0; c < 4; ++c) {
        float4 h = h4[c], s = s4[c], d = d4[c];
        as += h.x * s.x + h.y * s.y + h.z * s.z + h.w * s.w;
        ad += h.x * d.x + h.y * d.y + h.z * d.z + h.w * d.w;
    }
    a_s[idx] = as;
    a_d[idx] = ad;
}

// Wave-per-node GAT aggregation, 4 edge slots x 16 channel-groups (float4).
// Non-stabilized segment softmax: logits are O(1) here, exp is fp32-safe and
// Σexp(e)h/Σexp(e) is mathematically identical to the max-shifted form.
template <bool FINAL>
__global__ void gat_agg_w(const float* __restrict__ H, const int* __restrict__ row_ptr,
                          const int* __restrict__ csr, const float* __restrict__ a_s,
                          const float* __restrict__ a_d, const float* __restrict__ bias,
                          const float* __restrict__ Wl, const float* __restrict__ bl,
                          float* __restrict__ out, int n) {
    int idx = blockIdx.x * blockDim.x + threadIdx.x;
    int v = idx >> 6;
    int lane = idx & 63;
    if (v >= n) return;
    int cg = lane & 15;    // channel group: channels 4cg..4cg+3
    int slot = lane >> 4;  // edge slot 0..3
    int hd = cg >> 2;      // head
    const float4* H4 = (const float4*)H;

    float adv = a_d[v * 4 + hd];
    float l = 0.f;
    float4 acc = {0.f, 0.f, 0.f, 0.f};
    if (slot == 0) {  // self edge
        float e0 = a_s[v * 4 + hd] + adv;
        e0 = (e0 >= 0.f) ? e0 : 0.2f * e0;
        float p = __expf(e0);
        l = p;
        float4 h = H4[(size_t)v * 16 + cg];
        acc.x = p * h.x; acc.y = p * h.y; acc.z = p * h.z; acc.w = p * h.w;
    }
    int beg = row_ptr[v], end = row_ptr[v + 1];
    int deg = end - beg;
    int iters = (deg + 3) >> 2;
    int e = beg + slot;
    int u = (e < end) ? csr[e] : v;
    bool val = e < end;
    for (int i = 0; i < iters; ++i) {
        int en = e + 4;
        int un = (en < end) ? csr[en] : v;          // prefetch next index
        float ev = a_s[u * 4 + hd] + adv;
        ev = (ev >= 0.f) ? ev : 0.2f * ev;
        float p = val ? __expf(ev) : 0.f;
        float4 h = H4[(size_t)u * 16 + cg];
        l += p;
        acc.x = fmaf(p, h.x, acc.x);
        acc.y = fmaf(p, h.y, acc.y);
        acc.z = fmaf(p, h.z, acc.z);
        acc.w = fmaf(p, h.w, acc.w);
        e = en; u = un; val = en < end;
    }
    // reduce across the 4 slots (lanes differ in bits 4,5)
    for (int off = 16; off < 64; off <<= 1) {
        l += __shfl_xor(l, off);
        acc.x += __shfl_xor(acc.x, off);
        acc.y += __shfl_xor(acc.y, off);
        acc.z += __shfl_xor(acc.z, off);
        acc.w += __shfl_xor(acc.w, off);
    }
    float rl = 1.0f / (l + 1e-16f);
    if (!FINAL) {
        if (slot == 0) {
            float4 o;
            o.x = fmaxf(fmaf(acc.x, rl, bias[4 * cg + 0]), 0.f);
            o.y = fmaxf(fmaf(acc.y, rl, bias[4 * cg + 1]), 0.f);
            o.z = fmaxf(fmaf(acc.z, rl, bias[4 * cg + 2]), 0.f);
            o.w = fmaxf(fmaf(acc.w, rl, bias[4 * cg + 3]), 0.f);
            ((float4*)out)[(size_t)v * 16 + cg] = o;
        }
    } else {
        // fused final linear: out[v] = relu(Σ_c relu(h_c)*Wl_c + bl)
        float p = fmaxf(fmaf(acc.x, rl, bias[4 * cg + 0]), 0.f) * Wl[4 * cg + 0]
                + fmaxf(fmaf(acc.y, rl, bias[4 * cg + 1]), 0.f) * Wl[4 * cg + 1]
                + fmaxf(fmaf(acc.z, rl, bias[4 * cg + 2]), 0.f) * Wl[4 * cg + 2]
                + fmaxf(fmaf(acc.w, rl, bias[4 * cg + 3]), 0.f) * Wl[4 * cg + 3];
        p += __shfl_xor(p, 1);
        p += __shfl_xor(p, 2);
        p += __shfl_xor(p, 4);
        p += __shfl_xor(p, 8);
        if (lane == 0) out[v] = fmaxf(p + bl[0], 0.f);
    }
}

// ---------------- launch ----------------

extern "C" void kernel_launch(void* const* d_in, const int* in_sizes, int n_in,
                              void* d_out, int out_size, void* d_ws, size_t ws_size,
                              hipStream_t stream) {
    const float* x     = (const float*)d_in[0];
    const int*   ei    = (const int*)d_in[1];
    const float* W1    = (const float*)d_in[2];
    const float* b1    = (const float*)d_in[3];
    const float* W2    = (const float*)d_in[4];
    const float* b2    = (const float*)d_in[5];
    const float* W3    = (const float*)d_in[6];
    const float* b3    = (const float*)d_in[7];
    const float* Wg    = (const float*)d_in[8];
    const float* att_s = (const float*)d_in[9];
    const float* att_d = (const float*)d_in[10];
    const float* bg    = (const float*)d_in[11];
    const float* Wl    = (const float*)d_in[12];
    const float* bl    = (const float*)d_in[13];
    float* out = (float*)d_out;

    int n = in_sizes[0] / KIN;  // 100000
    int E = in_sizes[1] / 2;    // 1600000
    const int* srcp = ei;
    const int* dstp = ei + E;

    char* w = (char*)d_ws;
    auto alloc = [&](size_t bytes) -> void* {
        void* p = (void*)w;
        w += (bytes + 255) & ~(size_t)255;
        return p;
    };
    int*   cnt     = (int*)alloc((size_t)n * 4);
    int*   row_ptr = (int*)alloc((size_t)(n + 1) * 4);
    int*   fillc   = (int*)alloc((size_t)n * 4);
    int*   bsum    = (int*)alloc(512 * 4);
    int*   bpre    = (int*)alloc(512 * 4);
    int*   csr     = (int*)alloc((size_t)E * 4);
    float* dinv    = (float*)alloc((size_t)n * 4);
    float* a_s     = (float*)alloc((size_t)n * 4 * 4);
    float* a_d     = (float*)alloc((size_t)n * 4 * 4);
    float* bufA    = (float*)alloc((size_t)n * 64 * 4);
    float* bufB    = (float*)alloc((size_t)n * 64 * 4);
    float* bufC    = (float*)alloc((size_t)n * 64 * 4);

    hipMemsetAsync(cnt, 0, (size_t)n * 4, stream);
    hipMemsetAsync(fillc, 0, (size_t)n * 4, stream);

    int nb = (n + 255) / 256;
    count_dst<<<(E + 255) / 256, 256, 0, stream>>>(dstp, cnt, E);
    make_dinv<<<nb, 256, 0, stream>>>(cnt, dinv, n);
    scan_reduce<<<nb, 256, 0, stream>>>(cnt, bsum, n);
    scan_blocksums<<<1, 512, 0, stream>>>(bsum, bpre, nb);
    scan_scatter<<<nb, 256, 0, stream>>>(cnt, bpre, row_ptr, n, E);
    fill_csr<<<(E + 255) / 256, 256, 0, stream>>>(srcp, dstp, row_ptr, fillc, csr, E);

    int agg_blocks = (n * 64 + 255) / 256;

    // Layer 1: GCN 128->32
    gemm_rows<128, 32, true><<<(n + 7) / 8, 256, 0, stream>>>(x, W1, dinv, bufA, n);
    gcn_agg_w<32, false><<<agg_blocks, 256, 0, stream>>>(bufA, row_ptr, csr, dinv, b1, nullptr, bufB, n);
    // Layer 2: GCN 32->64
    gemm_rows<32, 64, true><<<(n + 3) / 4, 256, 0, stream>>>(bufB, W2, dinv, bufA, n);
    gcn_agg_w<64, false><<<agg_blocks, 256, 0, stream>>>(bufA, row_ptr, csr, dinv, b2, nullptr, bufB, n);
    // GAT 1
    gemm_rows<64, 64, false><<<(n + 3) / 4, 256, 0, stream>>>(bufB, Wg, nullptr, bufA, n);
    gat_att<<<(n * 4 + 255) / 256, 256, 0, stream>>>(bufA, att_s, att_d, a_s, a_d, n);
    gat_agg_w<false><<<agg_blocks, 256, 0, stream>>>(bufA, row_ptr, csr, a_s, a_d, bg, nullptr, nullptr, bufC, n);
    // GCN 3 + residual
    gemm_rows<64, 64, true><<<(n + 3) / 4, 256, 0, stream>>>(bufC, W3, dinv, bufA, n);
    gcn_agg_w<64, true><<<agg_blocks, 256, 0, stream>>>(bufA, row_ptr, csr, dinv, b3, bufC, bufB, n);
    // GAT 2 + fused final linear
    gemm_rows<64, 64, false><<<(n + 3) / 4, 256, 0, stream>>>(bufB, Wg, nullptr, bufA, n);
    gat_att<<<(n * 4 + 255) / 256, 256, 0, stream>>>(bufA, att_s, att_d, a_s, a_d, n);
    gat_agg_w<true><<<agg_blocks, 256, 0, stream>>>(bufA, row_ptr, csr, a_s, a_d, bg, Wl, bl, out, n);
}

// Round 3
// 829.542 us; speedup vs baseline: 1.5902x; 1.1573x over previous
//
#include <hip/hip_runtime.h>
#include <math.h>

constexpr int KIN = 128;   // IN_F

// ---------------- graph setup kernels ----------------

// count in-degree AND record each edge's within-dst rank (atomic return value).
__global__ void count_rank(const int* __restrict__ dst, int* __restrict__ cnt,
                           int* __restrict__ rank, int E) {
    int e = blockIdx.x * blockDim.x + threadIdx.x;
    if (e < E) rank[e] = atomicAdd(&cnt[dst[e]], 1);
}

// pass 1: per-block sums of cnt; also emit dinv
__global__ void scan_reduce_dinv(const int* __restrict__ cnt, int* __restrict__ bsum,
                                 float* __restrict__ dinv, int n) {
    __shared__ int s[256];
    int t = threadIdx.x;
    int i = blockIdx.x * 256 + t;
    int c = (i < n) ? cnt[i] : 0;
    if (i < n) dinv[i] = 1.0f / sqrtf((float)(c + 1));  // +1 self loop
    s[t] = c;
    __syncthreads();
    for (int off = 128; off > 0; off >>= 1) {
        if (t < off) s[t] += s[t + off];
        __syncthreads();
    }
    if (t == 0) bsum[blockIdx.x] = s[0];
}

__global__ void scan_blocksums(const int* __restrict__ bsum, int* __restrict__ bpre, int nb) {
    __shared__ int s[512];
    int t = threadIdx.x;
    int val = (t < nb) ? bsum[t] : 0;
    s[t] = val;
    __syncthreads();
    for (int off = 1; off < 512; off <<= 1) {
        int x = (t >= off) ? s[t - off] : 0;
        __syncthreads();
        s[t] += x;
        __syncthreads();
    }
    if (t < nb) bpre[t] = s[t] - val;  // exclusive
}

__global__ void scan_scatter(const int* __restrict__ cnt, const int* __restrict__ bpre,
                             int* __restrict__ row_ptr, int n, int total) {
    __shared__ int s[256];
    int t = threadIdx.x;
    int i = blockIdx.x * 256 + t;
    int val = (i < n) ? cnt[i] : 0;
    s[t] = val;
    __syncthreads();
    for (int off = 1; off < 256; off <<= 1) {
        int x = (t >= off) ? s[t - off] : 0;
        __syncthreads();
        s[t] += x;
        __syncthreads();
    }
    if (i < n) row_ptr[i] = bpre[blockIdx.x] + s[t] - val;
    if (i == n - 1) row_ptr[n] = total;
}

// atomic-free scatter: position = row_ptr[dst] + precomputed rank
__global__ void fill_csr(const int* __restrict__ src, const int* __restrict__ dst,
                         const int* __restrict__ rank, const int* __restrict__ row_ptr,
                         int* __restrict__ csr_src, int E) {
    int e = blockIdx.x * blockDim.x + threadIdx.x;
    if (e < E) {
        int d = dst[e];
        csr_src[row_ptr[d] + rank[e]] = src[e];
    }
}

// ---------------- dense kernels ----------------

// out[v,f] = (SCALE ? dinv[v] : 1) * sum_k in[v,k]*W[k,f]
// ATT (F==64 only): one wave == one row; fuse GAT attention dots a_s/a_d.
template <int K, int F, bool SCALE, bool ATT>
__global__ void gemm_rows(const float* __restrict__ in, const float* __restrict__ W,
                          const float* __restrict__ dinv, const float* __restrict__ att_src,
                          const float* __restrict__ att_dst, float* __restrict__ a_s,
                          float* __restrict__ a_d, float* __restrict__ out, int n) {
    __shared__ float Ws[K * F];
    int t = threadIdx.x;
    for (int i = t; i < K * F; i += 256) Ws[i] = W[i];
    __syncthreads();
    constexpr int ROWS = 256 / F;
    int v = blockIdx.x * ROWS + t / F;
    int f = t % F;
    if (v >= n) return;
    const float4* in4 = (const float4*)(in + (size_t)v * K);
    float acc = 0.f;
#pragma unroll
    for (int k4 = 0; k4 < K / 4; ++k4) {
        float4 a = in4[k4];
        acc = fmaf(a.x, Ws[(4 * k4 + 0) * F + f], acc);
        acc = fmaf(a.y, Ws[(4 * k4 + 1) * F + f], acc);
        acc = fmaf(a.z, Ws[(4 * k4 + 2) * F + f], acc);
        acc = fmaf(a.w, Ws[(4 * k4 + 3) * F + f], acc);
    }
    if (SCALE) acc *= dinv[v];
    out[(size_t)v * F + f] = acc;
    if (ATT) {
        // F==64: lanes 0..63 of this wave hold h[v,0..63]; head = f>>4.
        int hd = f >> 4;
        float ps = acc * att_src[f];  // att_src laid out [H,16] flat == [64]
        float pd = acc * att_dst[f];
        ps += __shfl_xor(ps, 1);  pd += __shfl_xor(pd, 1);
        ps += __shfl_xor(ps, 2);  pd += __shfl_xor(pd, 2);
        ps += __shfl_xor(ps, 4);  pd += __shfl_xor(pd, 4);
        ps += __shfl_xor(ps, 8);  pd += __shfl_xor(pd, 8);
        if ((f & 15) == 0) {
            a_s[v * 4 + hd] = ps;
            a_d[v * 4 + hd] = pd;
        }
    }
}

// Wave-per-node GCN aggregation, SLOTS edge slots x CG float4 channel groups,
// one-deep software pipeline on the gather.
template <int F, bool RES>
__global__ void gcn_agg_w(const float* __restrict__ Hs, const int* __restrict__ row_ptr,
                          const int* __restrict__ csr, const float* __restrict__ dinv,
                          const float* __restrict__ bias, const float* __restrict__ res,
                          float* __restrict__ out, int n) {
    constexpr int CG = F / 4;
    constexpr int SLOTS = 64 / CG;
    int idx = blockIdx.x * blockDim.x + threadIdx.x;
    int v = idx >> 6;
    int lane = idx & 63;
    if (v >= n) return;
    int cg = lane % CG;
    int slot = lane / CG;
    const float4* H4 = (const float4*)Hs;

    float4 acc = {0.f, 0.f, 0.f, 0.f};
    if (slot == 0) acc = H4[(size_t)v * CG + cg];  // self loop (pre-scaled by dinv[v])

    int beg = row_ptr[v], end = row_ptr[v + 1];
    int deg = end - beg;
    int iters = (deg + SLOTS - 1) / SLOTS;
    int e = beg + slot;
    bool val = e < end;
    int u = val ? csr[e] : v;
    float4 h = H4[(size_t)u * CG + cg];
    for (int i = 0; i < iters; ++i) {
        int en = e + SLOTS;
        bool valn = en < end;
        int un = valn ? csr[en] : v;
        float4 hn = H4[(size_t)un * CG + cg];   // in flight while we consume h
        float m = val ? 1.f : 0.f;
        acc.x = fmaf(m, h.x, acc.x);
        acc.y = fmaf(m, h.y, acc.y);
        acc.z = fmaf(m, h.z, acc.z);
        acc.w = fmaf(m, h.w, acc.w);
        e = en; val = valn; h = hn;
    }
    for (int off = CG; off < 64; off <<= 1) {
        acc.x += __shfl_xor(acc.x, off);
        acc.y += __shfl_xor(acc.y, off);
        acc.z += __shfl_xor(acc.z, off);
        acc.w += __shfl_xor(acc.w, off);
    }
    if (slot == 0) {
        float dv = dinv[v];
        float4 o;
        o.x = fmaxf(fmaf(dv, acc.x, bias[4 * cg + 0]), 0.f);
        o.y = fmaxf(fmaf(dv, acc.y, bias[4 * cg + 1]), 0.f);
        o.z = fmaxf(fmaf(dv, acc.z, bias[4 * cg + 2]), 0.f);
        o.w = fmaxf(fmaf(dv, acc.w, bias[4 * cg + 3]), 0.f);
        if (RES) {
            const float4 r = ((const float4*)res)[(size_t)v * CG + cg];
            o.x += r.x; o.y += r.y; o.z += r.z; o.w += r.w;
        }
        ((float4*)out)[(size_t)v * CG + cg] = o;
    }
}

// Wave-per-node GAT aggregation, 4 edge slots x 16 float4 channel groups,
// non-stabilized segment softmax (logits O(1), fp32-exact), pipelined gather.
template <bool FINAL>
__global__ void gat_agg_w(const float* __restrict__ H, const int* __restrict__ row_ptr,
                          const int* __restrict__ csr, const float* __restrict__ a_s,
                          const float* __restrict__ a_d, const float* __restrict__ bias,
                          const float* __restrict__ Wl, const float* __restrict__ bl,
                          float* __restrict__ out, int n) {
    int idx = blockIdx.x * blockDim.x + threadIdx.x;
    int v = idx >> 6;
    int lane = idx & 63;
    if (v >= n) return;
    int cg = lane & 15;    // channel group: channels 4cg..4cg+3
    int slot = lane >> 4;  // edge slot 0..3
    int hd = cg >> 2;      // head
    const float4* H4 = (const float4*)H;

    float adv = a_d[v * 4 + hd];
    float l = 0.f;
    float4 acc = {0.f, 0.f, 0.f, 0.f};
    if (slot == 0) {  // self edge
        float e0 = a_s[v * 4 + hd] + adv;
        e0 = (e0 >= 0.f) ? e0 : 0.2f * e0;
        float p = __expf(e0);
        l = p;
        float4 h = H4[(size_t)v * 16 + cg];
        acc.x = p * h.x; acc.y = p * h.y; acc.z = p * h.z; acc.w = p * h.w;
    }
    int beg = row_ptr[v], end = row_ptr[v + 1];
    int deg = end - beg;
    int iters = (deg + 3) >> 2;
    int e = beg + slot;
    bool val = e < end;
    int u = val ? csr[e] : v;
    float4 h = H4[(size_t)u * 16 + cg];
    float as = a_s[u * 4 + hd];
    for (int i = 0; i < iters; ++i) {
        int en = e + 4;
        bool valn = en < end;
        int un = valn ? csr[en] : v;
        float4 hn = H4[(size_t)un * 16 + cg];   // in flight while we consume h
        float asn = a_s[un * 4 + hd];
        float ev = as + adv;
        ev = (ev >= 0.f) ? ev : 0.2f * ev;
        float p = val ? __expf(ev) : 0.f;
        l += p;
        acc.x = fmaf(p, h.x, acc.x);
        acc.y = fmaf(p, h.y, acc.y);
        acc.z = fmaf(p, h.z, acc.z);
        acc.w = fmaf(p, h.w, acc.w);
        e = en; val = valn; h = hn; as = asn;
    }
    for (int off = 16; off < 64; off <<= 1) {
        l += __shfl_xor(l, off);
        acc.x += __shfl_xor(acc.x, off);
        acc.y += __shfl_xor(acc.y, off);
        acc.z += __shfl_xor(acc.z, off);
        acc.w += __shfl_xor(acc.w, off);
    }
    float rl = 1.0f / (l + 1e-16f);
    if (!FINAL) {
        if (slot == 0) {
            float4 o;
            o.x = fmaxf(fmaf(acc.x, rl, bias[4 * cg + 0]), 0.f);
            o.y = fmaxf(fmaf(acc.y, rl, bias[4 * cg + 1]), 0.f);
            o.z = fmaxf(fmaf(acc.z, rl, bias[4 * cg + 2]), 0.f);
            o.w = fmaxf(fmaf(acc.w, rl, bias[4 * cg + 3]), 0.f);
            ((float4*)out)[(size_t)v * 16 + cg] = o;
        }
    } else {
        // fused final linear: out[v] = relu(Σ_c relu(h_c)*Wl_c + bl)
        float p = fmaxf(fmaf(acc.x, rl, bias[4 * cg + 0]), 0.f) * Wl[4 * cg + 0]
                + fmaxf(fmaf(acc.y, rl, bias[4 * cg + 1]), 0.f) * Wl[4 * cg + 1]
                + fmaxf(fmaf(acc.z, rl, bias[4 * cg + 2]), 0.f) * Wl[4 * cg + 2]
                + fmaxf(fmaf(acc.w, rl, bias[4 * cg + 3]), 0.f) * Wl[4 * cg + 3];
        p += __shfl_xor(p, 1);
        p += __shfl_xor(p, 2);
        p += __shfl_xor(p, 4);
        p += __shfl_xor(p, 8);
        if (lane == 0) out[v] = fmaxf(p + bl[0], 0.f);
    }
}

// ---------------- launch ----------------

extern "C" void kernel_launch(void* const* d_in, const int* in_sizes, int n_in,
                              void* d_out, int out_size, void* d_ws, size_t ws_size,
                              hipStream_t stream) {
    const float* x     = (const float*)d_in[0];
    const int*   ei    = (const int*)d_in[1];
    const float* W1    = (const float*)d_in[2];
    const float* b1    = (const float*)d_in[3];
    const float* W2    = (const float*)d_in[4];
    const float* b2    = (const float*)d_in[5];
    const float* W3    = (const float*)d_in[6];
    const float* b3    = (const float*)d_in[7];
    const float* Wg    = (const float*)d_in[8];
    const float* att_s = (const float*)d_in[9];
    const float* att_d = (const float*)d_in[10];
    const float* bg    = (const float*)d_in[11];
    const float* Wl    = (const float*)d_in[12];
    const float* bl    = (const float*)d_in[13];
    float* out = (float*)d_out;

    int n = in_sizes[0] / KIN;  // 100000
    int E = in_sizes[1] / 2;    // 1600000
    const int* srcp = ei;
    const int* dstp = ei + E;

    char* w = (char*)d_ws;
    auto alloc = [&](size_t bytes) -> void* {
        void* p = (void*)w;
        w += (bytes + 255) & ~(size_t)255;
        return p;
    };
    int*   cnt     = (int*)alloc((size_t)n * 4);
    int*   row_ptr = (int*)alloc((size_t)(n + 1) * 4);
    int*   rank    = (int*)alloc((size_t)E * 4);
    int*   bsum    = (int*)alloc(512 * 4);
    int*   bpre    = (int*)alloc(512 * 4);
    int*   csr     = (int*)alloc((size_t)E * 4);
    float* dinv    = (float*)alloc((size_t)n * 4);
    float* a_s     = (float*)alloc((size_t)n * 4 * 4);
    float* a_d     = (float*)alloc((size_t)n * 4 * 4);
    float* bufA    = (float*)alloc((size_t)n * 64 * 4);
    float* bufB    = (float*)alloc((size_t)n * 64 * 4);
    float* bufC    = (float*)alloc((size_t)n * 64 * 4);

    hipMemsetAsync(cnt, 0, (size_t)n * 4, stream);

    int nb = (n + 255) / 256;
    count_rank<<<(E + 255) / 256, 256, 0, stream>>>(dstp, cnt, rank, E);
    scan_reduce_dinv<<<nb, 256, 0, stream>>>(cnt, bsum, dinv, n);
    scan_blocksums<<<1, 512, 0, stream>>>(bsum, bpre, nb);
    scan_scatter<<<nb, 256, 0, stream>>>(cnt, bpre, row_ptr, n, E);
    fill_csr<<<(E + 255) / 256, 256, 0, stream>>>(srcp, dstp, rank, row_ptr, csr, E);

    int agg_blocks = (n * 64 + 255) / 256;

    // Layer 1: GCN 128->32
    gemm_rows<128, 32, true, false><<<(n + 7) / 8, 256, 0, stream>>>(x, W1, dinv, nullptr, nullptr, nullptr, nullptr, bufA, n);
    gcn_agg_w<32, false><<<agg_blocks, 256, 0, stream>>>(bufA, row_ptr, csr, dinv, b1, nullptr, bufB, n);
    // Layer 2: GCN 32->64
    gemm_rows<32, 64, true, false><<<(n + 3) / 4, 256, 0, stream>>>(bufB, W2, dinv, nullptr, nullptr, nullptr, nullptr, bufA, n);
    gcn_agg_w<64, false><<<agg_blocks, 256, 0, stream>>>(bufA, row_ptr, csr, dinv, b2, nullptr, bufB, n);
    // GAT 1 (gemm + fused attention dots)
    gemm_rows<64, 64, false, true><<<(n + 3) / 4, 256, 0, stream>>>(bufB, Wg, nullptr, att_s, att_d, a_s, a_d, bufA, n);
    gat_agg_w<false><<<agg_blocks, 256, 0, stream>>>(bufA, row_ptr, csr, a_s, a_d, bg, nullptr, nullptr, bufC, n);
    // GCN 3 + residual
    gemm_rows<64, 64, true, false><<<(n + 3) / 4, 256, 0, stream>>>(bufC, W3, dinv, nullptr, nullptr, nullptr, nullptr, bufA, n);
    gcn_agg_w<64, true><<<agg_blocks, 256, 0, stream>>>(bufA, row_ptr, csr, dinv, b3, bufC, bufB, n);
    // GAT 2 (gemm + fused attention dots) + fused final linear
    gemm_rows<64, 64, false, true><<<(n + 3) / 4, 256, 0, stream>>>(bufB, Wg, nullptr, att_s, att_d, a_s, a_d, bufA, n);
    gat_agg_w<true><<<agg_blocks, 256, 0, stream>>>(bufA, row_ptr, csr, a_s, a_d, bg, Wl, bl, out, n);
}

// Round 4
// 619.677 us; speedup vs baseline: 2.1288x; 1.3387x over previous
//
#include <hip/hip_runtime.h>
#include <math.h>

constexpr int KIN = 128;   // IN_F

// ---------------- graph setup kernels ----------------

__global__ void count_rank(const int* __restrict__ dst, int* __restrict__ cnt,
                           int* __restrict__ rank, int E) {
    int e = blockIdx.x * blockDim.x + threadIdx.x;
    if (e < E) rank[e] = atomicAdd(&cnt[dst[e]], 1);
}

__global__ void scan_reduce_dinv(const int* __restrict__ cnt, int* __restrict__ bsum,
                                 float* __restrict__ dinv, int n) {
    __shared__ int s[256];
    int t = threadIdx.x;
    int i = blockIdx.x * 256 + t;
    int c = (i < n) ? cnt[i] : 0;
    if (i < n) dinv[i] = 1.0f / sqrtf((float)(c + 1));  // +1 self loop
    s[t] = c;
    __syncthreads();
    for (int off = 128; off > 0; off >>= 1) {
        if (t < off) s[t] += s[t + off];
        __syncthreads();
    }
    if (t == 0) bsum[blockIdx.x] = s[0];
}

__global__ void scan_blocksums(const int* __restrict__ bsum, int* __restrict__ bpre, int nb) {
    __shared__ int s[512];
    int t = threadIdx.x;
    int val = (t < nb) ? bsum[t] : 0;
    s[t] = val;
    __syncthreads();
    for (int off = 1; off < 512; off <<= 1) {
        int x = (t >= off) ? s[t - off] : 0;
        __syncthreads();
        s[t] += x;
        __syncthreads();
    }
    if (t < nb) bpre[t] = s[t] - val;  // exclusive
}

__global__ void scan_scatter(const int* __restrict__ cnt, const int* __restrict__ bpre,
                             int* __restrict__ row_ptr, int n, int total) {
    __shared__ int s[256];
    int t = threadIdx.x;
    int i = blockIdx.x * 256 + t;
    int val = (i < n) ? cnt[i] : 0;
    s[t] = val;
    __syncthreads();
    for (int off = 1; off < 256; off <<= 1) {
        int x = (t >= off) ? s[t - off] : 0;
        __syncthreads();
        s[t] += x;
        __syncthreads();
    }
    if (i < n) row_ptr[i] = bpre[blockIdx.x] + s[t] - val;
    if (i == n - 1) row_ptr[n] = total;
}

__global__ void fill_csr(const int* __restrict__ src, const int* __restrict__ dst,
                         const int* __restrict__ rank, const int* __restrict__ row_ptr,
                         int* __restrict__ csr_src, int E) {
    int e = blockIdx.x * blockDim.x + threadIdx.x;
    if (e < E) {
        int d = dst[e];
        csr_src[row_ptr[d] + rank[e]] = src[e];
    }
}

// ---------------- tiled register-blocked GEMM ----------------
// Block computes BM rows x F cols. x staged transposed in LDS (xs[k][r]),
// W staged in LDS. Thread micro-tile 4x4: per k-step 2 ds_read_b128 + 16 FMA.
// ATT (F==64): fuse GAT attention dots in epilogue.
template <int K, int F, int BM, int THREADS, bool SCALE, bool ATT>
__global__ void __launch_bounds__(THREADS)
gemm_tile(const float* __restrict__ in, const float* __restrict__ W,
          const float* __restrict__ dinv, const float* __restrict__ att_src,
          const float* __restrict__ att_dst, float* __restrict__ a_s,
          float* __restrict__ a_d, float* __restrict__ out, int n) {
    constexpr int TM = 4, TN = 4;
    constexpr int TX = F / TN;   // threads along cols
    constexpr int TY = BM / TM;  // threads along rows
    static_assert(THREADS == TX * TY, "thread count mismatch");
    constexpr int K4 = K / 4;
    __shared__ float xs[K][BM];    // transposed x tile
    __shared__ float Ws[K * F];
    int t = threadIdx.x;
    int row0 = blockIdx.x * BM;

    for (int i = t; i < K * F / 4; i += THREADS)
        ((float4*)Ws)[i] = ((const float4*)W)[i];

    // stage x transposed; consecutive lanes -> consecutive rows (conflict-free LDS writes)
    for (int i = t; i < BM * K4; i += THREADS) {
        int r = i % BM, k4 = i / BM;
        int row = row0 + r;
        float4 v = {0.f, 0.f, 0.f, 0.f};
        if (row < n) v = ((const float4*)(in + (size_t)row * K))[k4];
        xs[4 * k4 + 0][r] = v.x;
        xs[4 * k4 + 1][r] = v.y;
        xs[4 * k4 + 2][r] = v.z;
        xs[4 * k4 + 3][r] = v.w;
    }
    __syncthreads();

    int tx = t % TX, ty = t / TX;
    float acc[TM][TN] = {};
#pragma unroll 4
    for (int k = 0; k < K; ++k) {
        float4 xv = *(const float4*)&xs[k][ty * TM];
        float4 wv = *(const float4*)&Ws[k * F + tx * TN];
        float xr[4] = {xv.x, xv.y, xv.z, xv.w};
        float wr[4] = {wv.x, wv.y, wv.z, wv.w};
#pragma unroll
        for (int i = 0; i < TM; ++i)
#pragma unroll
            for (int j = 0; j < TN; ++j)
                acc[i][j] = fmaf(xr[i], wr[j], acc[i][j]);
    }

    // epilogue
#pragma unroll
    for (int i = 0; i < TM; ++i) {
        int row = row0 + ty * TM + i;
        if (row >= n) continue;
        float s = SCALE ? dinv[row] : 1.0f;
        float4 o;
        o.x = acc[i][0] * s; o.y = acc[i][1] * s;
        o.z = acc[i][2] * s; o.w = acc[i][3] * s;
        ((float4*)(out + (size_t)row * F))[tx] = o;
    }
    if (ATT) {
        // cols 4tx..4tx+3 lie in head hd = tx/4; reduce over the 4 tx within head.
        int hd = tx >> 2;
        float as0 = att_src[4 * tx + 0], as1 = att_src[4 * tx + 1];
        float as2 = att_src[4 * tx + 2], as3 = att_src[4 * tx + 3];
        float ad0 = att_dst[4 * tx + 0], ad1 = att_dst[4 * tx + 1];
        float ad2 = att_dst[4 * tx + 2], ad3 = att_dst[4 * tx + 3];
#pragma unroll
        for (int i = 0; i < TM; ++i) {
            float ps = acc[i][0] * as0 + acc[i][1] * as1 + acc[i][2] * as2 + acc[i][3] * as3;
            float pd = acc[i][0] * ad0 + acc[i][1] * ad1 + acc[i][2] * ad2 + acc[i][3] * ad3;
            ps += __shfl_xor(ps, 1); pd += __shfl_xor(pd, 1);
            ps += __shfl_xor(ps, 2); pd += __shfl_xor(pd, 2);
            int row = row0 + ty * TM + i;
            if ((tx & 3) == 0 && row < n) {
                a_s[row * 4 + hd] = ps;
                a_d[row * 4 + hd] = pd;
            }
        }
    }
}

// ---------------- aggregation kernels ----------------

template <int F, bool RES>
__global__ void gcn_agg_w(const float* __restrict__ Hs, const int* __restrict__ row_ptr,
                          const int* __restrict__ csr, const float* __restrict__ dinv,
                          const float* __restrict__ bias, const float* __restrict__ res,
                          float* __restrict__ out, int n) {
    constexpr int CG = F / 4;
    constexpr int SLOTS = 64 / CG;
    int idx = blockIdx.x * blockDim.x + threadIdx.x;
    int v = idx >> 6;
    int lane = idx & 63;
    if (v >= n) return;
    int cg = lane % CG;
    int slot = lane / CG;
    const float4* H4 = (const float4*)Hs;

    float4 acc = {0.f, 0.f, 0.f, 0.f};
    if (slot == 0) acc = H4[(size_t)v * CG + cg];  // self loop (pre-scaled by dinv[v])

    int beg = row_ptr[v], end = row_ptr[v + 1];
    int deg = end - beg;
    int iters = (deg + SLOTS - 1) / SLOTS;
    int e = beg + slot;
    bool val = e < end;
    int u = val ? csr[e] : v;
    float4 h = H4[(size_t)u * CG + cg];
    for (int i = 0; i < iters; ++i) {
        int en = e + SLOTS;
        bool valn = en < end;
        int un = valn ? csr[en] : v;
        float4 hn = H4[(size_t)un * CG + cg];   // in flight while we consume h
        float m = val ? 1.f : 0.f;
        acc.x = fmaf(m, h.x, acc.x);
        acc.y = fmaf(m, h.y, acc.y);
        acc.z = fmaf(m, h.z, acc.z);
        acc.w = fmaf(m, h.w, acc.w);
        e = en; val = valn; h = hn;
    }
    for (int off = CG; off < 64; off <<= 1) {
        acc.x += __shfl_xor(acc.x, off);
        acc.y += __shfl_xor(acc.y, off);
        acc.z += __shfl_xor(acc.z, off);
        acc.w += __shfl_xor(acc.w, off);
    }
    if (slot == 0) {
        float dv = dinv[v];
        float4 o;
        o.x = fmaxf(fmaf(dv, acc.x, bias[4 * cg + 0]), 0.f);
        o.y = fmaxf(fmaf(dv, acc.y, bias[4 * cg + 1]), 0.f);
        o.z = fmaxf(fmaf(dv, acc.z, bias[4 * cg + 2]), 0.f);
        o.w = fmaxf(fmaf(dv, acc.w, bias[4 * cg + 3]), 0.f);
        if (RES) {
            const float4 r = ((const float4*)res)[(size_t)v * CG + cg];
            o.x += r.x; o.y += r.y; o.z += r.z; o.w += r.w;
        }
        ((float4*)out)[(size_t)v * CG + cg] = o;
    }
}

template <bool FINAL>
__global__ void gat_agg_w(const float* __restrict__ H, const int* __restrict__ row_ptr,
                          const int* __restrict__ csr, const float* __restrict__ a_s,
                          const float* __restrict__ a_d, const float* __restrict__ bias,
                          const float* __restrict__ Wl, const float* __restrict__ bl,
                          float* __restrict__ out, int n) {
    int idx = blockIdx.x * blockDim.x + threadIdx.x;
    int v = idx >> 6;
    int lane = idx & 63;
    if (v >= n) return;
    int cg = lane & 15;    // channel group
    int slot = lane >> 4;  // edge slot 0..3
    int hd = cg >> 2;      // head
    const float4* H4 = (const float4*)H;

    float adv = a_d[v * 4 + hd];
    float l = 0.f;
    float4 acc = {0.f, 0.f, 0.f, 0.f};
    if (slot == 0) {  // self edge
        float e0 = a_s[v * 4 + hd] + adv;
        e0 = (e0 >= 0.f) ? e0 : 0.2f * e0;
        float p = __expf(e0);
        l = p;
        float4 h = H4[(size_t)v * 16 + cg];
        acc.x = p * h.x; acc.y = p * h.y; acc.z = p * h.z; acc.w = p * h.w;
    }
    int beg = row_ptr[v], end = row_ptr[v + 1];
    int deg = end - beg;
    int iters = (deg + 3) >> 2;
    int e = beg + slot;
    bool val = e < end;
    int u = val ? csr[e] : v;
    float4 h = H4[(size_t)u * 16 + cg];
    float as = a_s[u * 4 + hd];
    for (int i = 0; i < iters; ++i) {
        int en = e + 4;
        bool valn = en < end;
        int un = valn ? csr[en] : v;
        float4 hn = H4[(size_t)un * 16 + cg];   // in flight while we consume h
        float asn = a_s[un * 4 + hd];
        float ev = as + adv;
        ev = (ev >= 0.f) ? ev : 0.2f * ev;
        float p = val ? __expf(ev) : 0.f;
        l += p;
        acc.x = fmaf(p, h.x, acc.x);
        acc.y = fmaf(p, h.y, acc.y);
        acc.z = fmaf(p, h.z, acc.z);
        acc.w = fmaf(p, h.w, acc.w);
        e = en; val = valn; h = hn; as = asn;
    }
    for (int off = 16; off < 64; off <<= 1) {
        l += __shfl_xor(l, off);
        acc.x += __shfl_xor(acc.x, off);
        acc.y += __shfl_xor(acc.y, off);
        acc.z += __shfl_xor(acc.z, off);
        acc.w += __shfl_xor(acc.w, off);
    }
    float rl = 1.0f / (l + 1e-16f);
    if (!FINAL) {
        if (slot == 0) {
            float4 o;
            o.x = fmaxf(fmaf(acc.x, rl, bias[4 * cg + 0]), 0.f);
            o.y = fmaxf(fmaf(acc.y, rl, bias[4 * cg + 1]), 0.f);
            o.z = fmaxf(fmaf(acc.z, rl, bias[4 * cg + 2]), 0.f);
            o.w = fmaxf(fmaf(acc.w, rl, bias[4 * cg + 3]), 0.f);
            ((float4*)out)[(size_t)v * 16 + cg] = o;
        }
    } else {
        float p = fmaxf(fmaf(acc.x, rl, bias[4 * cg + 0]), 0.f) * Wl[4 * cg + 0]
                + fmaxf(fmaf(acc.y, rl, bias[4 * cg + 1]), 0.f) * Wl[4 * cg + 1]
                + fmaxf(fmaf(acc.z, rl, bias[4 * cg + 2]), 0.f) * Wl[4 * cg + 2]
                + fmaxf(fmaf(acc.w, rl, bias[4 * cg + 3]), 0.f) * Wl[4 * cg + 3];
        p += __shfl_xor(p, 1);
        p += __shfl_xor(p, 2);
        p += __shfl_xor(p, 4);
        p += __shfl_xor(p, 8);
        if (lane == 0) out[v] = fmaxf(p + bl[0], 0.f);
    }
}

// ---------------- launch ----------------

extern "C" void kernel_launch(void* const* d_in, const int* in_sizes, int n_in,
                              void* d_out, int out_size, void* d_ws, size_t ws_size,
                              hipStream_t stream) {
    const float* x     = (const float*)d_in[0];
    const int*   ei    = (const int*)d_in[1];
    const float* W1    = (const float*)d_in[2];
    const float* b1    = (const float*)d_in[3];
    const float* W2    = (const float*)d_in[4];
    const float* b2    = (const float*)d_in[5];
    const float* W3    = (const float*)d_in[6];
    const float* b3    = (const float*)d_in[7];
    const float* Wg    = (const float*)d_in[8];
    const float* att_s = (const float*)d_in[9];
    const float* att_d = (const float*)d_in[10];
    const float* bg    = (const float*)d_in[11];
    const float* Wl    = (const float*)d_in[12];
    const float* bl    = (const float*)d_in[13];
    float* out = (float*)d_out;

    int n = in_sizes[0] / KIN;  // 100000
    int E = in_sizes[1] / 2;    // 1600000
    const int* srcp = ei;
    const int* dstp = ei + E;

    char* w = (char*)d_ws;
    auto alloc = [&](size_t bytes) -> void* {
        void* p = (void*)w;
        w += (bytes + 255) & ~(size_t)255;
        return p;
    };
    int*   cnt     = (int*)alloc((size_t)n * 4);
    int*   row_ptr = (int*)alloc((size_t)(n + 1) * 4);
    int*   rank    = (int*)alloc((size_t)E * 4);
    int*   bsum    = (int*)alloc(512 * 4);
    int*   bpre    = (int*)alloc(512 * 4);
    int*   csr     = (int*)alloc((size_t)E * 4);
    float* dinv    = (float*)alloc((size_t)n * 4);
    float* a_s     = (float*)alloc((size_t)n * 4 * 4);
    float* a_d     = (float*)alloc((size_t)n * 4 * 4);
    float* bufA    = (float*)alloc((size_t)n * 64 * 4);
    float* bufB    = (float*)alloc((size_t)n * 64 * 4);
    float* bufC    = (float*)alloc((size_t)n * 64 * 4);

    hipMemsetAsync(cnt, 0, (size_t)n * 4, stream);

    int nb = (n + 255) / 256;
    count_rank<<<(E + 255) / 256, 256, 0, stream>>>(dstp, cnt, rank, E);
    scan_reduce_dinv<<<nb, 256, 0, stream>>>(cnt, bsum, dinv, n);
    scan_blocksums<<<1, 512, 0, stream>>>(bsum, bpre, nb);
    scan_scatter<<<nb, 256, 0, stream>>>(cnt, bpre, row_ptr, n, E);
    fill_csr<<<(E + 255) / 256, 256, 0, stream>>>(srcp, dstp, rank, row_ptr, csr, E);

    int agg_blocks = (n * 64 + 255) / 256;
    int gemm_blocks = (n + 63) / 64;

    // Layer 1: GCN 128->32
    gemm_tile<128, 32, 64, 128, true, false><<<gemm_blocks, 128, 0, stream>>>(
        x, W1, dinv, nullptr, nullptr, nullptr, nullptr, bufA, n);
    gcn_agg_w<32, false><<<agg_blocks, 256, 0, stream>>>(bufA, row_ptr, csr, dinv, b1, nullptr, bufB, n);
    // Layer 2: GCN 32->64
    gemm_tile<32, 64, 64, 256, true, false><<<gemm_blocks, 256, 0, stream>>>(
        bufB, W2, dinv, nullptr, nullptr, nullptr, nullptr, bufA, n);
    gcn_agg_w<64, false><<<agg_blocks, 256, 0, stream>>>(bufA, row_ptr, csr, dinv, b2, nullptr, bufB, n);
    // GAT 1 (gemm + fused attention dots)
    gemm_tile<64, 64, 64, 256, false, true><<<gemm_blocks, 256, 0, stream>>>(
        bufB, Wg, nullptr, att_s, att_d, a_s, a_d, bufA, n);
    gat_agg_w<false><<<agg_blocks, 256, 0, stream>>>(bufA, row_ptr, csr, a_s, a_d, bg, nullptr, nullptr, bufC, n);
    // GCN 3 + residual
    gemm_tile<64, 64, 64, 256, true, false><<<gemm_blocks, 256, 0, stream>>>(
        bufC, W3, dinv, nullptr, nullptr, nullptr, nullptr, bufA, n);
    gcn_agg_w<64, true><<<agg_blocks, 256, 0, stream>>>(bufA, row_ptr, csr, dinv, b3, bufC, bufB, n);
    // GAT 2 (gemm + fused attention dots) + fused final linear
    gemm_tile<64, 64, 64, 256, false, true><<<gemm_blocks, 256, 0, stream>>>(
        bufB, Wg, nullptr, att_s, att_d, a_s, a_d, bufA, n);
    gat_agg_w<true><<<agg_blocks, 256, 0, stream>>>(bufA, row_ptr, csr, a_s, a_d, bg, Wl, bl, out, n);
}

// Round 5
// 602.002 us; speedup vs baseline: 2.1913x; 1.0294x over previous
//
#include <hip/hip_runtime.h>
#include <math.h>

constexpr int KIN = 128;   // IN_F

// ---------------- graph setup kernels ----------------

__global__ void count_rank(const int* __restrict__ dst, int* __restrict__ cnt,
                           int* __restrict__ rank, int E) {
    int e = blockIdx.x * blockDim.x + threadIdx.x;
    if (e < E) rank[e] = atomicAdd(&cnt[dst[e]], 1);
}

__global__ void scan_reduce_dinv(const int* __restrict__ cnt, int* __restrict__ bsum,
                                 float* __restrict__ dinv, int n) {
    __shared__ int s[256];
    int t = threadIdx.x;
    int i = blockIdx.x * 256 + t;
    int c = (i < n) ? cnt[i] : 0;
    if (i < n) dinv[i] = 1.0f / sqrtf((float)(c + 1));  // +1 self loop
    s[t] = c;
    __syncthreads();
    for (int off = 128; off > 0; off >>= 1) {
        if (t < off) s[t] += s[t + off];
        __syncthreads();
    }
    if (t == 0) bsum[blockIdx.x] = s[0];
}

__global__ void scan_blocksums(const int* __restrict__ bsum, int* __restrict__ bpre, int nb) {
    __shared__ int s[512];
    int t = threadIdx.x;
    int val = (t < nb) ? bsum[t] : 0;
    s[t] = val;
    __syncthreads();
    for (int off = 1; off < 512; off <<= 1) {
        int x = (t >= off) ? s[t - off] : 0;
        __syncthreads();
        s[t] += x;
        __syncthreads();
    }
    if (t < nb) bpre[t] = s[t] - val;  // exclusive
}

__global__ void scan_scatter(const int* __restrict__ cnt, const int* __restrict__ bpre,
                             int* __restrict__ row_ptr, int n, int total) {
    __shared__ int s[256];
    int t = threadIdx.x;
    int i = blockIdx.x * 256 + t;
    int val = (i < n) ? cnt[i] : 0;
    s[t] = val;
    __syncthreads();
    for (int off = 1; off < 256; off <<= 1) {
        int x = (t >= off) ? s[t - off] : 0;
        __syncthreads();
        s[t] += x;
        __syncthreads();
    }
    if (i < n) row_ptr[i] = bpre[blockIdx.x] + s[t] - val;
    if (i == n - 1) row_ptr[n] = total;
}

__global__ void fill_csr(const int* __restrict__ src, const int* __restrict__ dst,
                         const int* __restrict__ rank, const int* __restrict__ row_ptr,
                         int* __restrict__ csr_src, int E) {
    int e = blockIdx.x * blockDim.x + threadIdx.x;
    if (e < E) {
        int d = dst[e];
        csr_src[row_ptr[d] + rank[e]] = src[e];
    }
}

// ---------------- tiled register-blocked GEMM ----------------
template <int K, int F, int BM, int THREADS, bool SCALE, bool BRELU, bool ATT>
__global__ void __launch_bounds__(THREADS)
gemm_tile(const float* __restrict__ in, const float* __restrict__ W,
          const float* __restrict__ dinv, const float* __restrict__ bias,
          const float* __restrict__ att_src, const float* __restrict__ att_dst,
          float* __restrict__ a_s, float* __restrict__ a_d,
          float* __restrict__ out, int n) {
    constexpr int TM = 4, TN = 4;
    constexpr int TX = F / TN;
    constexpr int TY = BM / TM;
    static_assert(THREADS == TX * TY, "thread count mismatch");
    constexpr int K4 = K / 4;
    __shared__ float xs[K][BM];
    __shared__ float Ws[K * F];
    int t = threadIdx.x;
    int row0 = blockIdx.x * BM;

    for (int i = t; i < K * F / 4; i += THREADS)
        ((float4*)Ws)[i] = ((const float4*)W)[i];

    for (int i = t; i < BM * K4; i += THREADS) {
        int r = i % BM, k4 = i / BM;
        int row = row0 + r;
        float4 v = {0.f, 0.f, 0.f, 0.f};
        if (row < n) v = ((const float4*)(in + (size_t)row * K))[k4];
        xs[4 * k4 + 0][r] = v.x;
        xs[4 * k4 + 1][r] = v.y;
        xs[4 * k4 + 2][r] = v.z;
        xs[4 * k4 + 3][r] = v.w;
    }
    __syncthreads();

    int tx = t % TX, ty = t / TX;
    float acc[TM][TN] = {};
#pragma unroll 4
    for (int k = 0; k < K; ++k) {
        float4 xv = *(const float4*)&xs[k][ty * TM];
        float4 wv = *(const float4*)&Ws[k * F + tx * TN];
        float xr[4] = {xv.x, xv.y, xv.z, xv.w};
        float wr[4] = {wv.x, wv.y, wv.z, wv.w};
#pragma unroll
        for (int i = 0; i < TM; ++i)
#pragma unroll
            for (int j = 0; j < TN; ++j)
                acc[i][j] = fmaf(xr[i], wr[j], acc[i][j]);
    }

#pragma unroll
    for (int i = 0; i < TM; ++i) {
        int row = row0 + ty * TM + i;
        if (row >= n) continue;
        float s = SCALE ? dinv[row] : 1.0f;
        float4 o;
        if (BRELU) {
            o.x = fmaxf(fmaf(acc[i][0], s, bias[4 * tx + 0]), 0.f);
            o.y = fmaxf(fmaf(acc[i][1], s, bias[4 * tx + 1]), 0.f);
            o.z = fmaxf(fmaf(acc[i][2], s, bias[4 * tx + 2]), 0.f);
            o.w = fmaxf(fmaf(acc[i][3], s, bias[4 * tx + 3]), 0.f);
        } else {
            o.x = acc[i][0] * s; o.y = acc[i][1] * s;
            o.z = acc[i][2] * s; o.w = acc[i][3] * s;
        }
        ((float4*)(out + (size_t)row * F))[tx] = o;
    }
    if (ATT) {
        int hd = tx >> 2;
        float as0 = att_src[4 * tx + 0], as1 = att_src[4 * tx + 1];
        float as2 = att_src[4 * tx + 2], as3 = att_src[4 * tx + 3];
        float ad0 = att_dst[4 * tx + 0], ad1 = att_dst[4 * tx + 1];
        float ad2 = att_dst[4 * tx + 2], ad3 = att_dst[4 * tx + 3];
#pragma unroll
        for (int i = 0; i < TM; ++i) {
            float ps = acc[i][0] * as0 + acc[i][1] * as1 + acc[i][2] * as2 + acc[i][3] * as3;
            float pd = acc[i][0] * ad0 + acc[i][1] * ad1 + acc[i][2] * ad2 + acc[i][3] * ad3;
            ps += __shfl_xor(ps, 1); pd += __shfl_xor(pd, 1);
            ps += __shfl_xor(ps, 2); pd += __shfl_xor(pd, 2);
            int row = row0 + ty * TM + i;
            if ((tx & 3) == 0 && row < n) {
                a_s[row * 4 + hd] = ps;
                a_d[row * 4 + hd] = pd;
            }
        }
    }
}

// ---------------- aggregation kernels ----------------
// MODE 0: out = relu(dinv*acc + b) (+res)   — standard GCN epilogue
// MODE 1: out = dinv * relu(dinv*acc + b)   — emit next layer's pre-scaled G
// MODE 2: out = acc                          — raw sum (epilogue in next GEMM)
template <int F, int MODE, bool RES>
__global__ void gcn_agg_w(const float* __restrict__ Hs, const int* __restrict__ row_ptr,
                          const int* __restrict__ csr, const float* __restrict__ dinv,
                          const float* __restrict__ bias, const float* __restrict__ res,
                          float* __restrict__ out, int n) {
    constexpr int CG = F / 4;
    constexpr int SLOTS = 64 / CG;
    int idx = blockIdx.x * blockDim.x + threadIdx.x;
    int v = idx >> 6;
    int lane = idx & 63;
    if (v >= n) return;
    int cg = lane % CG;
    int slot = lane / CG;
    const float4* H4 = (const float4*)Hs;

    float4 acc = {0.f, 0.f, 0.f, 0.f};
    if (slot == 0) acc = H4[(size_t)v * CG + cg];  // self loop

    int beg = row_ptr[v], end = row_ptr[v + 1];
    int deg = end - beg;
    int iters = (deg + SLOTS - 1) / SLOTS;
    // depth-2 pipelined gather
    int e = beg + slot;
    bool v0 = e < end;  int u0 = v0 ? csr[e] : v;  float4 h0 = H4[(size_t)u0 * CG + cg];  e += SLOTS;
    bool v1 = e < end;  int u1 = v1 ? csr[e] : v;  float4 h1 = H4[(size_t)u1 * CG + cg];  e += SLOTS;
    for (int i = 0; i < iters; i += 2) {
        bool v2 = e < end;  int u2 = v2 ? csr[e] : v;  float4 h2 = H4[(size_t)u2 * CG + cg];  e += SLOTS;
        bool v3 = e < end;  int u3 = v3 ? csr[e] : v;  float4 h3 = H4[(size_t)u3 * CG + cg];  e += SLOTS;
        float m0 = v0 ? 1.f : 0.f;
        acc.x = fmaf(m0, h0.x, acc.x); acc.y = fmaf(m0, h0.y, acc.y);
        acc.z = fmaf(m0, h0.z, acc.z); acc.w = fmaf(m0, h0.w, acc.w);
        float m1 = v1 ? 1.f : 0.f;
        acc.x = fmaf(m1, h1.x, acc.x); acc.y = fmaf(m1, h1.y, acc.y);
        acc.z = fmaf(m1, h1.z, acc.z); acc.w = fmaf(m1, h1.w, acc.w);
        v0 = v2; h0 = h2; v1 = v3; h1 = h3;
    }
    for (int off = CG; off < 64; off <<= 1) {
        acc.x += __shfl_xor(acc.x, off);
        acc.y += __shfl_xor(acc.y, off);
        acc.z += __shfl_xor(acc.z, off);
        acc.w += __shfl_xor(acc.w, off);
    }
    if (slot == 0) {
        float4 o;
        if (MODE == 2) {
            o = acc;
        } else {
            float dv = dinv[v];
            o.x = fmaxf(fmaf(dv, acc.x, bias[4 * cg + 0]), 0.f);
            o.y = fmaxf(fmaf(dv, acc.y, bias[4 * cg + 1]), 0.f);
            o.z = fmaxf(fmaf(dv, acc.z, bias[4 * cg + 2]), 0.f);
            o.w = fmaxf(fmaf(dv, acc.w, bias[4 * cg + 3]), 0.f);
            if (MODE == 1) { o.x *= dv; o.y *= dv; o.z *= dv; o.w *= dv; }
            if (RES) {
                const float4 r = ((const float4*)res)[(size_t)v * CG + cg];
                o.x += r.x; o.y += r.y; o.z += r.z; o.w += r.w;
            }
        }
        ((float4*)out)[(size_t)v * CG + cg] = o;
    }
}

template <bool FINAL>
__global__ void gat_agg_w(const float* __restrict__ H, const int* __restrict__ row_ptr,
                          const int* __restrict__ csr, const float* __restrict__ a_s,
                          const float* __restrict__ a_d, const float* __restrict__ bias,
                          const float* __restrict__ Wl, const float* __restrict__ bl,
                          float* __restrict__ out, int n) {
    int idx = blockIdx.x * blockDim.x + threadIdx.x;
    int v = idx >> 6;
    int lane = idx & 63;
    if (v >= n) return;
    int cg = lane & 15;
    int slot = lane >> 4;
    int hd = cg >> 2;
    const float4* H4 = (const float4*)H;

    float adv = a_d[v * 4 + hd];
    float l = 0.f;
    float4 acc = {0.f, 0.f, 0.f, 0.f};
    if (slot == 0) {  // self edge
        float e0 = a_s[v * 4 + hd] + adv;
        e0 = (e0 >= 0.f) ? e0 : 0.2f * e0;
        float p = __expf(e0);
        l = p;
        float4 h = H4[(size_t)v * 16 + cg];
        acc.x = p * h.x; acc.y = p * h.y; acc.z = p * h.z; acc.w = p * h.w;
    }
    int beg = row_ptr[v], end = row_ptr[v + 1];
    int deg = end - beg;
    int iters = (deg + 3) >> 2;
    // depth-2 pipelined gather
    int e = beg + slot;
    bool v0 = e < end;  int u0 = v0 ? csr[e] : v;
    float4 h0 = H4[(size_t)u0 * 16 + cg];  float s0 = a_s[u0 * 4 + hd];  e += 4;
    bool v1 = e < end;  int u1 = v1 ? csr[e] : v;
    float4 h1 = H4[(size_t)u1 * 16 + cg];  float s1 = a_s[u1 * 4 + hd];  e += 4;
    for (int i = 0; i < iters; i += 2) {
        bool v2 = e < end;  int u2 = v2 ? csr[e] : v;
        float4 h2 = H4[(size_t)u2 * 16 + cg];  float s2 = a_s[u2 * 4 + hd];  e += 4;
        bool v3 = e < end;  int u3 = v3 ? csr[e] : v;
        float4 h3 = H4[(size_t)u3 * 16 + cg];  float s3 = a_s[u3 * 4 + hd];  e += 4;
        {
            float ev = s0 + adv;
            ev = (ev >= 0.f) ? ev : 0.2f * ev;
            float p = v0 ? __expf(ev) : 0.f;
            l += p;
            acc.x = fmaf(p, h0.x, acc.x); acc.y = fmaf(p, h0.y, acc.y);
            acc.z = fmaf(p, h0.z, acc.z); acc.w = fmaf(p, h0.w, acc.w);
        }
        {
            float ev = s1 + adv;
            ev = (ev >= 0.f) ? ev : 0.2f * ev;
            float p = v1 ? __expf(ev) : 0.f;
            l += p;
            acc.x = fmaf(p, h1.x, acc.x); acc.y = fmaf(p, h1.y, acc.y);
            acc.z = fmaf(p, h1.z, acc.z); acc.w = fmaf(p, h1.w, acc.w);
        }
        v0 = v2; h0 = h2; s0 = s2; v1 = v3; h1 = h3; s1 = s3;
    }
    for (int off = 16; off < 64; off <<= 1) {
        l += __shfl_xor(l, off);
        acc.x += __shfl_xor(acc.x, off);
        acc.y += __shfl_xor(acc.y, off);
        acc.z += __shfl_xor(acc.z, off);
        acc.w += __shfl_xor(acc.w, off);
    }
    float rl = 1.0f / (l + 1e-16f);
    if (!FINAL) {
        if (slot == 0) {
            float4 o;
            o.x = fmaxf(fmaf(acc.x, rl, bias[4 * cg + 0]), 0.f);
            o.y = fmaxf(fmaf(acc.y, rl, bias[4 * cg + 1]), 0.f);
            o.z = fmaxf(fmaf(acc.z, rl, bias[4 * cg + 2]), 0.f);
            o.w = fmaxf(fmaf(acc.w, rl, bias[4 * cg + 3]), 0.f);
            ((float4*)out)[(size_t)v * 16 + cg] = o;
        }
    } else {
        float p = fmaxf(fmaf(acc.x, rl, bias[4 * cg + 0]), 0.f) * Wl[4 * cg + 0]
                + fmaxf(fmaf(acc.y, rl, bias[4 * cg + 1]), 0.f) * Wl[4 * cg + 1]
                + fmaxf(fmaf(acc.z, rl, bias[4 * cg + 2]), 0.f) * Wl[4 * cg + 2]
                + fmaxf(fmaf(acc.w, rl, bias[4 * cg + 3]), 0.f) * Wl[4 * cg + 3];
        p += __shfl_xor(p, 1);
        p += __shfl_xor(p, 2);
        p += __shfl_xor(p, 4);
        p += __shfl_xor(p, 8);
        if (lane == 0) out[v] = fmaxf(p + bl[0], 0.f);
    }
}

// ---------------- launch ----------------

extern "C" void kernel_launch(void* const* d_in, const int* in_sizes, int n_in,
                              void* d_out, int out_size, void* d_ws, size_t ws_size,
                              hipStream_t stream) {
    const float* x     = (const float*)d_in[0];
    const int*   ei    = (const int*)d_in[1];
    const float* W1    = (const float*)d_in[2];
    const float* b1    = (const float*)d_in[3];
    const float* W2    = (const float*)d_in[4];
    const float* b2    = (const float*)d_in[5];
    const float* W3    = (const float*)d_in[6];
    const float* b3    = (const float*)d_in[7];
    const float* Wg    = (const float*)d_in[8];
    const float* att_s = (const float*)d_in[9];
    const float* att_d = (const float*)d_in[10];
    const float* bg    = (const float*)d_in[11];
    const float* Wl    = (const float*)d_in[12];
    const float* bl    = (const float*)d_in[13];
    float* out = (float*)d_out;

    int n = in_sizes[0] / KIN;  // 100000
    int E = in_sizes[1] / 2;    // 1600000
    const int* srcp = ei;
    const int* dstp = ei + E;

    char* w = (char*)d_ws;
    auto alloc = [&](size_t bytes) -> void* {
        void* p = (void*)w;
        w += (bytes + 255) & ~(size_t)255;
        return p;
    };
    int*   cnt     = (int*)alloc((size_t)n * 4);
    int*   row_ptr = (int*)alloc((size_t)(n + 1) * 4);
    int*   rank    = (int*)alloc((size_t)E * 4);
    int*   bsum    = (int*)alloc(512 * 4);
    int*   bpre    = (int*)alloc(512 * 4);
    int*   csr     = (int*)alloc((size_t)E * 4);
    float* dinv    = (float*)alloc((size_t)n * 4);
    float* a_s     = (float*)alloc((size_t)n * 4 * 4);
    float* a_d     = (float*)alloc((size_t)n * 4 * 4);
    float* bufA    = (float*)alloc((size_t)n * 64 * 4);
    float* bufB    = (float*)alloc((size_t)n * 64 * 4);
    float* bufC    = (float*)alloc((size_t)n * 64 * 4);

    hipMemsetAsync(cnt, 0, (size_t)n * 4, stream);

    int nb = (n + 255) / 256;
    count_rank<<<(E + 255) / 256, 256, 0, stream>>>(dstp, cnt, rank, E);
    scan_reduce_dinv<<<nb, 256, 0, stream>>>(cnt, bsum, dinv, n);
    scan_blocksums<<<1, 512, 0, stream>>>(bsum, bpre, nb);
    scan_scatter<<<nb, 256, 0, stream>>>(cnt, bpre, row_ptr, n, E);
    fill_csr<<<(E + 255) / 256, 256, 0, stream>>>(srcp, dstp, rank, row_ptr, csr, E);

    int agg_blocks = (n * 64 + 255) / 256;
    int gemm_blocks = (n + 63) / 64;

    // Layer 1: GCN 128->32. H1s = dinv⊙(X@W1); agg emits G = dinv*relu(dinv*agg+b1)
    gemm_tile<128, 32, 64, 128, true, false, false><<<gemm_blocks, 128, 0, stream>>>(
        x, W1, dinv, nullptr, nullptr, nullptr, nullptr, nullptr, bufA, n);
    gcn_agg_w<32, 1, false><<<agg_blocks, 256, 0, stream>>>(bufA, row_ptr, csr, dinv, b1, nullptr, bufB, n);
    // Layer 2: aggregate G in 32-dim (raw sum), then GEMM applies dinv, b2, relu
    gcn_agg_w<32, 2, false><<<agg_blocks, 256, 0, stream>>>(bufB, row_ptr, csr, nullptr, nullptr, nullptr, bufA, n);
    gemm_tile<32, 64, 64, 256, true, true, false><<<gemm_blocks, 256, 0, stream>>>(
        bufA, W2, dinv, b2, nullptr, nullptr, nullptr, nullptr, bufB, n);
    // GAT 1 (gemm + fused attention dots)
    gemm_tile<64, 64, 64, 256, false, false, true><<<gemm_blocks, 256, 0, stream>>>(
        bufB, Wg, nullptr, nullptr, att_s, att_d, a_s, a_d, bufA, n);
    gat_agg_w<false><<<agg_blocks, 256, 0, stream>>>(bufA, row_ptr, csr, a_s, a_d, bg, nullptr, nullptr, bufC, n);
    // GCN 3 + residual
    gemm_tile<64, 64, 64, 256, true, false, false><<<gemm_blocks, 256, 0, stream>>>(
        bufC, W3, dinv, nullptr, nullptr, nullptr, nullptr, nullptr, bufA, n);
    gcn_agg_w<64, 0, true><<<agg_blocks, 256, 0, stream>>>(bufA, row_ptr, csr, dinv, b3, bufC, bufB, n);
    // GAT 2 (gemm + fused attention dots) + fused final linear
    gemm_tile<64, 64, 64, 256, false, false, true><<<gemm_blocks, 256, 0, stream>>>(
        bufB, Wg, nullptr, nullptr, att_s, att_d, a_s, a_d, bufA, n);
    gat_agg_w<true><<<agg_blocks, 256, 0, stream>>>(bufA, row_ptr, csr, a_s, a_d, bg, Wl, bl, out, n);
}